// Round 10
// baseline (102.091 us; speedup 1.0000x reference)
//
#include <hip/hip_runtime.h>

#define BN 2
#define T_DIM 2048
#define D_DIM 1024
#define H_N 16
#define DH_N 64
#define WIN 256
#define NROWS (BN * T_DIM)   // 4096
#define KDIM 1024            // inner dim for all GEMMs

typedef __attribute__((ext_vector_type(8))) short bf16x8;
typedef __attribute__((ext_vector_type(4))) float f32x4;
typedef __attribute__((ext_vector_type(16))) float f32x16;
typedef __attribute__((ext_vector_type(8))) unsigned short ushort8;
typedef __attribute__((ext_vector_type(4))) unsigned short u16x4;

static __device__ __forceinline__ unsigned short f2bf(float f) {
  unsigned int u = __float_as_uint(f);
  unsigned int r = (u + 0x7FFFu + ((u >> 16) & 1u)) >> 16;  // RNE
  return (unsigned short)r;
}

static __device__ __forceinline__ void gl_lds16(const void* g, void* l) {
  __builtin_amdgcn_global_load_lds(
      (const __attribute__((address_space(1))) unsigned int*)g,
      (__attribute__((address_space(3))) unsigned int*)l, 16, 0, 0);
}

#define MFMA16(a, b, c) __builtin_amdgcn_mfma_f32_16x16x32_bf16(a, b, c, 0, 0, 0)
#define MFMA32(a, b, c) __builtin_amdgcn_mfma_f32_32x32x16_bf16(a, b, c, 0, 0, 0)

// ---------------------------------------------------------------------------
// Merged conversions (one launch): x f32->bf16 (blocks 0..2047),
// w_qkv^T (2048..2815), w_out^T (2816..3071).
// ---------------------------------------------------------------------------
static __device__ __forceinline__ void transpose_tile(
    const float* __restrict__ src, unsigned short* __restrict__ dst, int R,
    int C, int bx, int by, float* tile /* [64][65] */) {
  const int t = threadIdx.x;
  const int bc = bx * 64, br = by * 64;
#pragma unroll
  for (int i = 0; i < 16; ++i) {
    int idx = i * 256 + t;
    int r = idx >> 6, c = idx & 63;
    tile[r * 65 + c] = src[(size_t)(br + r) * C + bc + c];
  }
  __syncthreads();
#pragma unroll
  for (int i = 0; i < 16; ++i) {
    int idx = i * 256 + t;
    int r = idx >> 6, c = idx & 63;
    dst[(size_t)(bc + r) * R + br + c] = f2bf(tile[c * 65 + r]);
  }
}

__global__ __launch_bounds__(256) void convert_all(
    const float* __restrict__ x, const float* __restrict__ w_qkv,
    const float* __restrict__ w_out, unsigned short* __restrict__ xbf,
    unsigned short* __restrict__ wqkvt, unsigned short* __restrict__ woutt) {
  __shared__ float tile[64 * 65];
  const int id = blockIdx.x;
  if (id < 2048) {
    int i = (id * 256 + threadIdx.x) * 8;
    float4 a = *(const float4*)(x + i);
    float4 b = *(const float4*)(x + i + 4);
    ushort8 o;
    o[0] = f2bf(a.x); o[1] = f2bf(a.y); o[2] = f2bf(a.z); o[3] = f2bf(a.w);
    o[4] = f2bf(b.x); o[5] = f2bf(b.y); o[6] = f2bf(b.z); o[7] = f2bf(b.w);
    *(ushort8*)(xbf + i) = o;
  } else if (id < 2816) {
    int j = id - 2048;  // 48 x 16
    transpose_tile(w_qkv, wqkvt, D_DIM, 3 * D_DIM, j % 48, j / 48, tile);
  } else {
    int j = id - 2816;  // 16 x 16
    transpose_tile(w_out, woutt, D_DIM, D_DIM, j % 16, j / 16, tile);
  }
}

// ---------------------------------------------------------------------------
// qkv GEMM v5: 256x192 tile, 4 waves (2Mx2N), per-wave 128x96 via
// mfma_f32_32x32x16_bf16 (12 frags x 16 f32 acc = 192 VGPR). BK=32,
// double-buffered 56KB LDS -> 2 blocks/CU. One barrier per K-tile, vmcnt(0)
// covered by previous iteration's compute + co-resident block. XCD map:
// 4 M-tiles x 8 N-tiles per XCD (A 2MB + B 3MB ~ L2-resident).
// Swizzle slot^((row>>1)&3) on 64B rows, both sides (pre-swizzled source).
// Epilogue: q,k bf16 [B,H,T,64] (q*0.125), v^T bf16 [B,H,64,T].
// ---------------------------------------------------------------------------
__global__ __launch_bounds__(256, 2) void gemm_qkv_32(
    const unsigned short* __restrict__ A, const unsigned short* __restrict__ Bt,
    const float* __restrict__ bias, unsigned short* __restrict__ qo,
    unsigned short* __restrict__ ko, unsigned short* __restrict__ vto) {
  __shared__ unsigned short As[2][256 * 32];  // 2 x 16 KB
  __shared__ unsigned short Bs[2][192 * 32];  // 2 x 12 KB

  const int tid = threadIdx.x;
  const int w = tid >> 6, l = tid & 63;
  const int wr = w >> 1, wc = w & 1;
  const int l31 = l & 31, lh = l >> 5;  // 32x32 frag: row/col = l&31, half = l>>5

  // XCD map: xcd = id&7 arranged 4x2; per XCD 32 blocks as 4 M x 8 N.
  const int id = blockIdx.x;
  const int xcd = id & 7, i = id >> 3;
  const int by = (xcd & 3) * 4 + (i & 3);
  const int bx = (xcd >> 2) * 8 + (i >> 2);
  const int r0 = by * 256, c0 = bx * 192;

  const unsigned short* Ag = A + (size_t)r0 * KDIM;
  const unsigned short* Bg = Bt + (size_t)c0 * KDIM;

  f32x16 acc[4][3];
#pragma unroll
  for (int mi = 0; mi < 4; ++mi)
#pragma unroll
    for (int ni = 0; ni < 3; ++ni)
#pragma unroll
      for (int r = 0; r < 16; ++r) acc[mi][ni][r] = 0.f;

  // staging: linear chunk ci -> row = ci>>2, slot = ci&3 (64B rows, 4 slots);
  // source slot pre-swizzled by (row>>1)&3 (involution matches read XOR).
#define STG(T, BUF)                                                            \
  do {                                                                         \
    const size_t kk0 = (size_t)(T) * 32;                                       \
    _Pragma("unroll") for (int i_ = 0; i_ < 4; ++i_) {                         \
      int ci = i_ * 256 + tid;                                                 \
      int row = ci >> 2, slot = ci & 3;                                        \
      gl_lds16(Ag + (size_t)row * KDIM + kk0 + ((slot ^ ((row >> 1) & 3)) * 8),\
               (char*)&As[BUF][0] + ci * 16);                                  \
    }                                                                          \
    _Pragma("unroll") for (int i_ = 0; i_ < 3; ++i_) {                         \
      int ci = i_ * 256 + tid;                                                 \
      int row = ci >> 2, slot = ci & 3;                                        \
      gl_lds16(Bg + (size_t)row * KDIM + kk0 + ((slot ^ ((row >> 1) & 3)) * 8),\
               (char*)&Bs[BUF][0] + ci * 16);                                  \
    }                                                                          \
  } while (0)

  // 32x32x16 fragment: lane holds row (l&31), k = (l>>5)*8 + 0..7 of k-half ks
#define LDA32(CB, mi, ks)                                                      \
  (*(const bf16x8*)((const char*)&As[CB][0] +                                  \
                    (wr * 128 + (mi)*32 + l31) * 64 +                          \
                    (((((ks)*2 + lh) ^ (((wr * 128 + (mi)*32 + l31) >> 1) & 3))) \
                     << 4)))
#define LDB32(CB, ni, ks)                                                      \
  (*(const bf16x8*)((const char*)&Bs[CB][0] +                                  \
                    (wc * 96 + (ni)*32 + l31) * 64 +                           \
                    (((((ks)*2 + lh) ^ (((wc * 96 + (ni)*32 + l31) >> 1) & 3))) \
                     << 4)))

#define KHALF(CB, ks)                                                          \
  do {                                                                         \
    bf16x8 a0 = LDA32(CB, 0, ks), a1 = LDA32(CB, 1, ks), a2 = LDA32(CB, 2, ks),\
           a3 = LDA32(CB, 3, ks);                                              \
    bf16x8 b0 = LDB32(CB, 0, ks), b1 = LDB32(CB, 1, ks), b2 = LDB32(CB, 2, ks);\
    __builtin_amdgcn_s_setprio(1);                                             \
    acc[0][0] = MFMA32(a0, b0, acc[0][0]);                                     \
    acc[0][1] = MFMA32(a0, b1, acc[0][1]);                                     \
    acc[0][2] = MFMA32(a0, b2, acc[0][2]);                                     \
    acc[1][0] = MFMA32(a1, b0, acc[1][0]);                                     \
    acc[1][1] = MFMA32(a1, b1, acc[1][1]);                                     \
    acc[1][2] = MFMA32(a1, b2, acc[1][2]);                                     \
    acc[2][0] = MFMA32(a2, b0, acc[2][0]);                                     \
    acc[2][1] = MFMA32(a2, b1, acc[2][1]);                                     \
    acc[2][2] = MFMA32(a2, b2, acc[2][2]);                                     \
    acc[3][0] = MFMA32(a3, b0, acc[3][0]);                                     \
    acc[3][1] = MFMA32(a3, b1, acc[3][1]);                                     \
    acc[3][2] = MFMA32(a3, b2, acc[3][2]);                                     \
    __builtin_amdgcn_s_setprio(0);                                             \
  } while (0)

  STG(0, 0);
#pragma unroll 2
  for (int t = 0; t < 31; ++t) {
    const int cb = t & 1;
    asm volatile("s_waitcnt vmcnt(0)" ::: "memory");  // tile-t landed (covered)
    __builtin_amdgcn_s_barrier();  // + all waves done reading buf cb^1
    STG(t + 1, cb ^ 1);
    KHALF(cb, 0);
    KHALF(cb, 1);
  }
  asm volatile("s_waitcnt vmcnt(0)" ::: "memory");
  __builtin_amdgcn_s_barrier();
  KHALF(1, 0);
  KHALF(1, 1);
#undef STG
#undef LDA32
#undef LDB32
#undef KHALF

  // epilogue: 32x32 C/D layout (m74/m101): col = l&31,
  // row = (reg&3) + 8*(reg>>2) + 4*(l>>5)
#pragma unroll
  for (int ni = 0; ni < 3; ++ni) {
    const int col0 = c0 + wc * 96 + ni * 32;  // 32-aligned -> single head
    const int which = col0 >> 10;             // 0=q,1=k,2=v
    const int h = (col0 >> 6) & 15;
    const int dh = (col0 & 63) + l31;
    const float bv = bias[col0 + l31];
#pragma unroll
    for (int mi = 0; mi < 4; ++mi) {
      const int rbase = r0 + wr * 128 + mi * 32 + 4 * lh;
#pragma unroll
      for (int q = 0; q < 4; ++q) {
        int row = rbase + 8 * q;  // multiple of 4
        int b_ = row >> 11, t0 = row & 2047;
        if (which == 2) {
          u16x4 pk;
#pragma unroll
          for (int j = 0; j < 4; ++j) pk[j] = f2bf(acc[mi][ni][q * 4 + j] + bv);
          *(u16x4*)(vto + ((size_t)(b_ * H_N + h) * DH_N + dh) * T_DIM + t0) = pk;
        } else {
          float mul = (which == 0) ? 0.125f : 1.0f;
          unsigned short* dst = (which == 0) ? qo : ko;
#pragma unroll
          for (int j = 0; j < 4; ++j)
            dst[((size_t)(b_ * H_N + h) * T_DIM + t0 + j) * DH_N + dh] =
                f2bf((acc[mi][ni][q * 4 + j] + bv) * mul);
        }
      }
    }
  }
}

// ---------------------------------------------------------------------------
// out-proj GEMM (unchanged): 128x128, quad-buffer, lead-2, one barrier/iter,
// counted vmcnt(8).
// ---------------------------------------------------------------------------
__global__ __launch_bounds__(256) void gemm_out_p4(
    const unsigned short* __restrict__ A, const unsigned short* __restrict__ Bt,
    const float* __restrict__ bias, float* __restrict__ fo) {
  __shared__ unsigned short As[4][4096];
  __shared__ unsigned short Bs[4][4096];

  const int tid = threadIdx.x;
  const int w = tid >> 6, l = tid & 63;
  const int wr = w >> 1, wc = w & 1;
  const int l15 = l & 15, kslc = l >> 4;

  const int id = blockIdx.x;
  const int wg = (id & 7) * 32 + (id >> 3);
  const int bx = wg & 7, by = wg >> 3;
  const int r0 = by * 128, c0 = bx * 128;

  const unsigned short* Ag = A + (size_t)r0 * KDIM;
  const unsigned short* Bg = Bt + (size_t)c0 * KDIM;

  f32x4 acc[4][4];
#pragma unroll
  for (int i = 0; i < 4; ++i)
#pragma unroll
    for (int j = 0; j < 4; ++j) acc[i][j] = (f32x4){0.f, 0.f, 0.f, 0.f};

  const int srow = l >> 2;
  const int srcslot = (l & 3) ^ ((l >> 3) & 3);

#define STAGE_O(T, BUF)                                                        \
  do {                                                                         \
    const size_t kk0 = (size_t)(T) * 32;                                       \
    gl_lds16(Ag + (size_t)(w * 16 + srow) * KDIM + kk0 + srcslot * 8,          \
             (char*)&As[BUF][0] + w * 1024);                                   \
    gl_lds16(Ag + (size_t)(64 + w * 16 + srow) * KDIM + kk0 + srcslot * 8,     \
             (char*)&As[BUF][0] + (4 + w) * 1024);                             \
    gl_lds16(Bg + (size_t)(w * 16 + srow) * KDIM + kk0 + srcslot * 8,          \
             (char*)&Bs[BUF][0] + w * 1024);                                   \
    gl_lds16(Bg + (size_t)(64 + w * 16 + srow) * KDIM + kk0 + srcslot * 8,     \
             (char*)&Bs[BUF][0] + (4 + w) * 1024);                             \
  } while (0)

#define OCOMPUTE(CB)                                                           \
  do {                                                                         \
    bf16x8 af[4], bfr[4];                                                      \
    _Pragma("unroll") for (int mi = 0; mi < 4; ++mi) {                         \
      int row = wr * 64 + mi * 16 + l15;                                       \
      af[mi] = *(const bf16x8*)((const char*)&As[CB][0] + row * 64 +           \
                                ((kslc ^ ((row >> 1) & 3)) << 4));             \
    }                                                                          \
    _Pragma("unroll") for (int ni = 0; ni < 4; ++ni) {                         \
      int row = wc * 64 + ni * 16 + l15;                                       \
      bfr[ni] = *(const bf16x8*)((const char*)&Bs[CB][0] + row * 64 +          \
                                 ((kslc ^ ((row >> 1) & 3)) << 4));            \
    }                                                                          \
    __builtin_amdgcn_s_setprio(1);                                             \
    _Pragma("unroll") for (int mi = 0; mi < 4; ++mi)                           \
        _Pragma("unroll") for (int ni = 0; ni < 4; ++ni) acc[mi][ni] =         \
            MFMA16(af[mi], bfr[ni], acc[mi][ni]);                              \
    __builtin_amdgcn_s_setprio(0);                                             \
  } while (0)

  STAGE_O(0, 0);
  STAGE_O(1, 1);

  for (int t = 0; t < 30; ++t) {
    STAGE_O(t + 2, (t + 2) & 3);
    asm volatile("s_waitcnt vmcnt(8)" ::: "memory");
    __builtin_amdgcn_s_barrier();
    OCOMPUTE(t & 3);
  }
  asm volatile("s_waitcnt vmcnt(4)" ::: "memory");
  __builtin_amdgcn_s_barrier();
  OCOMPUTE(2);
  asm volatile("s_waitcnt vmcnt(0)" ::: "memory");
  __builtin_amdgcn_s_barrier();
  OCOMPUTE(3);
#undef STAGE_O
#undef OCOMPUTE

#pragma unroll
  for (int mi = 0; mi < 4; ++mi) {
#pragma unroll
    for (int ni = 0; ni < 4; ++ni) {
      int row = r0 + wr * 64 + mi * 16 + (l >> 4) * 4;
      int col = c0 + wc * 64 + ni * 16 + l15;
      float bv = bias[col];
#pragma unroll
      for (int j = 0; j < 4; ++j)
        fo[(size_t)(row + j) * D_DIM + col] = acc[mi][ni][j] + bv;
    }
  }
}

// ---------------------------------------------------------------------------
// MFMA windowed flash attention (unchanged from round 9).
// ---------------------------------------------------------------------------
__global__ __launch_bounds__(256) void attn_mfma(
    const unsigned short* __restrict__ qbf,
    const unsigned short* __restrict__ kbf,
    const unsigned short* __restrict__ vtbf,
    unsigned short* __restrict__ ctx) {
  __shared__ unsigned short Ks[2][64 * 64];
  __shared__ unsigned short Vs[2][64 * 64];
  const int tid = threadIdx.x;
  const int w = tid >> 6, l = tid & 63;
  const int g = l >> 4, ln = l & 15;
  const int qt = blockIdx.x & 31;
  const int bh = blockIdx.x >> 5;
  const int q0 = qt * 64;
  const int q_abs = q0 + w * 16 + ln;

  const unsigned short* kp = kbf + (size_t)bh * T_DIM * DH_N;
  const unsigned short* vtp = vtbf + (size_t)bh * DH_N * T_DIM;

  bf16x8 qf0, qf1;
  {
    const unsigned short* qp = qbf + ((size_t)bh * T_DIM + q_abs) * DH_N;
    qf0 = *(const bf16x8*)(qp + g * 8);
    qf1 = *(const bf16x8*)(qp + 32 + g * 8);
  }

#define KAP(row) \
  (32 * (((row) >> 4) & 1) + 8 * (((row)&15) >> 2) + 4 * ((row) >> 5) + ((row)&3))

#define STAGEKV(KT, BUF)                                                       \
  do {                                                                         \
    _Pragma("unroll") for (int i_ = 0; i_ < 2; ++i_) {                         \
      int chunk = i_ * 256 + tid;                                              \
      int row = chunk >> 3, c16 = chunk & 7;                                   \
      int sc16 = c16 ^ (row & 7);                                              \
      int kap = KAP(row);                                                      \
      gl_lds16(kp + (size_t)((KT) + kap) * DH_N + sc16 * 8,                    \
               (char*)&Ks[BUF][0] + chunk * 16);                               \
      gl_lds16(vtp + (size_t)row * T_DIM + (KT) + sc16 * 8,                    \
               (char*)&Vs[BUF][0] + chunk * 16);                               \
    }                                                                          \
  } while (0)

  f32x4 acc_o[4];
#pragma unroll
  for (int nd = 0; nd < 4; ++nd) acc_o[nd] = (f32x4){0.f, 0.f, 0.f, 0.f};
  float m = -1e30f, lsum = 0.f;

  const int kt_lo = (q0 >= WIN) ? (q0 - WIN) : 0;
  const int nt = ((q0 - kt_lo) >> 6) + 1;

  STAGEKV(kt_lo, 0);
  for (int i = 0; i < nt; ++i) {
    const int cb = i & 1;
    const int kt = kt_lo + i * 64;
    asm volatile("s_waitcnt vmcnt(0)" ::: "memory");
    __builtin_amdgcn_s_barrier();
    if (i + 1 < nt) STAGEKV(kt + 64, cb ^ 1);

    f32x4 sacc[4];
#pragma unroll
    for (int nk = 0; nk < 4; ++nk) sacc[nk] = (f32x4){0.f, 0.f, 0.f, 0.f};
#pragma unroll
    for (int ks = 0; ks < 2; ++ks) {
      bf16x8 qf = ks ? qf1 : qf0;
#pragma unroll
      for (int nk = 0; nk < 4; ++nk) {
        int rrow = nk * 16 + ln;
        int c16 = ks * 4 + g;
        bf16x8 kf = *(const bf16x8*)((const char*)&Ks[cb][0] + rrow * 128 +
                                     ((c16 ^ (rrow & 7)) * 16));
        sacc[nk] = MFMA16(kf, qf, sacc[nk]);
      }
    }

    float p[4][4];
    float tm = -1e30f;
#pragma unroll
    for (int nk = 0; nk < 4; ++nk)
#pragma unroll
      for (int j = 0; j < 4; ++j) {
        int k_abs = kt + 32 * (nk & 1) + 8 * g + 4 * (nk >> 1) + j;
        float s = sacc[nk][j];
        bool ok = (k_abs <= q_abs) && (k_abs + WIN >= q_abs);
        s = ok ? s : -1e30f;
        p[nk][j] = s;
        tm = fmaxf(tm, s);
      }
    tm = fmaxf(tm, __shfl_xor(tm, 16, 64));
    tm = fmaxf(tm, __shfl_xor(tm, 32, 64));
    float mn = fmaxf(m, tm);
    float sc = __expf(m - mn);
    float ps = 0.f;
#pragma unroll
    for (int nk = 0; nk < 4; ++nk)
#pragma unroll
      for (int j = 0; j < 4; ++j) {
        p[nk][j] = __expf(p[nk][j] - mn);
        ps += p[nk][j];
      }
    ps += __shfl_xor(ps, 16, 64);
    ps += __shfl_xor(ps, 32, 64);
    lsum = lsum * sc + ps;
    m = mn;
#pragma unroll
    for (int nd = 0; nd < 4; ++nd) {
      acc_o[nd][0] *= sc; acc_o[nd][1] *= sc;
      acc_o[nd][2] *= sc; acc_o[nd][3] *= sc;
    }

    unsigned int pk[4][2];
#pragma unroll
    for (int nk = 0; nk < 4; ++nk) {
      pk[nk][0] = (unsigned)f2bf(p[nk][0]) | ((unsigned)f2bf(p[nk][1]) << 16);
      pk[nk][1] = (unsigned)f2bf(p[nk][2]) | ((unsigned)f2bf(p[nk][3]) << 16);
    }

#pragma unroll
    for (int ks = 0; ks < 2; ++ks) {
      union { unsigned int d[4]; bf16x8 v; } pf;
      pf.d[0] = pk[ks][0];     pf.d[1] = pk[ks][1];
      pf.d[2] = pk[2 + ks][0]; pf.d[3] = pk[2 + ks][1];
#pragma unroll
      for (int nd = 0; nd < 4; ++nd) {
        int drow = nd * 16 + ln;
        int c16 = ks * 4 + g;
        bf16x8 vf = *(const bf16x8*)((const char*)&Vs[cb][0] + drow * 128 +
                                     ((c16 ^ (drow & 7)) * 16));
        acc_o[nd] = MFMA16(vf, pf.v, acc_o[nd]);
      }
    }
  }
#undef STAGEKV
#undef KAP

  float inv = 1.f / lsum;
  const int b_ = bh >> 4, h = bh & 15;
  unsigned short* op = ctx + ((size_t)b_ * T_DIM + q_abs) * D_DIM + h * DH_N;
#pragma unroll
  for (int nd = 0; nd < 4; ++nd) {
    u16x4 o;
#pragma unroll
    for (int j = 0; j < 4; ++j) o[j] = f2bf(acc_o[nd][j] * inv);
    *(u16x4*)(op + nd * 16 + g * 4) = o;
  }
}

// ---------------------------------------------------------------------------
extern "C" void kernel_launch(void* const* d_in, const int* in_sizes, int n_in,
                              void* d_out, int out_size, void* d_ws,
                              size_t ws_size, hipStream_t stream) {
  const float* x = (const float*)d_in[0];
  const float* w_qkv = (const float*)d_in[1];
  const float* b_qkv = (const float*)d_in[2];
  const float* w_out = (const float*)d_in[3];
  const float* b_out = (const float*)d_in[4];
  float* out = (float*)d_out;

  const size_t per = (size_t)BN * H_N * T_DIM * DH_N;  // 4,194,304
  unsigned short* qbf = (unsigned short*)d_ws;
  unsigned short* kbf = qbf + per;
  unsigned short* vtbf = kbf + per;                    // [B,H,64,T]
  unsigned short* xbf = vtbf + per;                    // [4096][1024]
  unsigned short* wqkvt = xbf + (size_t)NROWS * D_DIM; // [3072][1024]
  unsigned short* woutt = wqkvt + (size_t)3 * D_DIM * D_DIM;  // [1024][1024]
  unsigned short* ctxbf = woutt + (size_t)D_DIM * D_DIM;      // [4096][1024]

  convert_all<<<dim3(3072), dim3(256), 0, stream>>>(x, w_qkv, w_out, xbf,
                                                    wqkvt, woutt);

  // qkv: 256x192 tiles -> 16 x 16 = 256 blocks, 256 threads, 2 blocks/CU
  gemm_qkv_32<<<dim3(256), dim3(256), 0, stream>>>(xbf, wqkvt, b_qkv, qbf, kbf,
                                                   vtbf);

  attn_mfma<<<dim3(BN * H_N * (T_DIM / 64)), dim3(256), 0, stream>>>(
      qbf, kbf, vtbf, ctxbf);

  // out-proj: 128x128 tiles -> 32 x 8 = 256 blocks, 256 threads
  gemm_out_p4<<<dim3(256), dim3(256), 0, stream>>>(ctxbf, woutt, b_out, out);
}

// Round 11
// 92.276 us; speedup vs baseline: 1.1064x; 1.1064x over previous
//
#include <hip/hip_runtime.h>

#define BN 2
#define T_DIM 2048
#define D_DIM 1024
#define H_N 16
#define DH_N 64
#define WIN 256
#define NROWS (BN * T_DIM)   // 4096
#define KDIM 1024            // inner dim for all GEMMs

typedef __attribute__((ext_vector_type(8))) short bf16x8;
typedef __attribute__((ext_vector_type(4))) float f32x4;
typedef __attribute__((ext_vector_type(8))) unsigned short ushort8;
typedef __attribute__((ext_vector_type(4))) unsigned short u16x4;

static __device__ __forceinline__ unsigned short f2bf(float f) {
  unsigned int u = __float_as_uint(f);
  unsigned int r = (u + 0x7FFFu + ((u >> 16) & 1u)) >> 16;  // RNE
  return (unsigned short)r;
}

static __device__ __forceinline__ void gl_lds16(const void* g, void* l) {
  __builtin_amdgcn_global_load_lds(
      (const __attribute__((address_space(1))) unsigned int*)g,
      (__attribute__((address_space(3))) unsigned int*)l, 16, 0, 0);
}

#define MFMA16(a, b, c) __builtin_amdgcn_mfma_f32_16x16x32_bf16(a, b, c, 0, 0, 0)

// ---------------------------------------------------------------------------
// Merged conversions (one launch): x f32->bf16 (blocks 0..2047),
// w_qkv^T (2048..2815), w_out^T (2816..3071).
// ---------------------------------------------------------------------------
static __device__ __forceinline__ void transpose_tile(
    const float* __restrict__ src, unsigned short* __restrict__ dst, int R,
    int C, int bx, int by, float* tile /* [64][65] */) {
  const int t = threadIdx.x;
  const int bc = bx * 64, br = by * 64;
#pragma unroll
  for (int i = 0; i < 16; ++i) {
    int idx = i * 256 + t;
    int r = idx >> 6, c = idx & 63;
    tile[r * 65 + c] = src[(size_t)(br + r) * C + bc + c];
  }
  __syncthreads();
#pragma unroll
  for (int i = 0; i < 16; ++i) {
    int idx = i * 256 + t;
    int r = idx >> 6, c = idx & 63;
    dst[(size_t)(bc + r) * R + br + c] = f2bf(tile[c * 65 + r]);
  }
}

__global__ __launch_bounds__(256) void convert_all(
    const float* __restrict__ x, const float* __restrict__ w_qkv,
    const float* __restrict__ w_out, unsigned short* __restrict__ xbf,
    unsigned short* __restrict__ wqkvt, unsigned short* __restrict__ woutt) {
  __shared__ float tile[64 * 65];
  const int id = blockIdx.x;
  if (id < 2048) {
    int i = (id * 256 + threadIdx.x) * 8;
    float4 a = *(const float4*)(x + i);
    float4 b = *(const float4*)(x + i + 4);
    ushort8 o;
    o[0] = f2bf(a.x); o[1] = f2bf(a.y); o[2] = f2bf(a.z); o[3] = f2bf(a.w);
    o[4] = f2bf(b.x); o[5] = f2bf(b.y); o[6] = f2bf(b.z); o[7] = f2bf(b.w);
    *(ushort8*)(xbf + i) = o;
  } else if (id < 2816) {
    int j = id - 2048;  // 48 x 16
    transpose_tile(w_qkv, wqkvt, D_DIM, 3 * D_DIM, j % 48, j / 48, tile);
  } else {
    int j = id - 2816;  // 16 x 16
    transpose_tile(w_out, woutt, D_DIM, D_DIM, j % 16, j / 16, tile);
  }
}

// ---------------------------------------------------------------------------
// qkv GEMM (measured-best, round-8: 41.4us): 256x192 tile, grid 256 blocks,
// 8 waves (2M x 4N), per-wave 128x48. BK=64, double-buffered 112KB LDS,
// 4 phases per K-tile, counted vmcnt(2), XOR swizzle slot^(row&7) both sides.
// Epilogue: q,k bf16 [B,H,T,64] (q*0.125), v^T bf16 [B,H,64,T].
// ---------------------------------------------------------------------------
__global__ __launch_bounds__(512) void gemm_qkv_8p(
    const unsigned short* __restrict__ A, const unsigned short* __restrict__ Bt,
    const float* __restrict__ bias, unsigned short* __restrict__ qo,
    unsigned short* __restrict__ ko, unsigned short* __restrict__ vto) {
  __shared__ unsigned short As[2][256 * 64];  // 2 x 32 KB
  __shared__ unsigned short Bs[2][192 * 64];  // 2 x 24 KB

  const int tid = threadIdx.x;
  const int w = tid >> 6, l = tid & 63;
  const int wr = w >> 2, wc = w & 3;  // 2M x 4N waves, per-wave 128x48
  const int l15 = l & 15, kslc = l >> 4;

  // T1: bijective XCD swizzle (nwg = 256)
  const int id = blockIdx.x;
  const int wg = (id & 7) * 32 + (id >> 3);
  const int bx = wg & 15, by = wg >> 4;
  const int r0 = by * 256, c0 = bx * 192;

  const unsigned short* Ag = A + (size_t)r0 * KDIM;
  const unsigned short* Bg = Bt + (size_t)c0 * KDIM;

  f32x4 acc[8][3];
#pragma unroll
  for (int i = 0; i < 8; ++i)
#pragma unroll
    for (int j = 0; j < 3; ++j) acc[i][j] = (f32x4){0.f, 0.f, 0.f, 0.f};

  const int grow = tid >> 3;                 // row within 64-row chunk
  const int gcol = (tid & 7) ^ (grow & 7);   // pre-swizzled source slot

#define STAGE_A(T, BUF, CH)                                                    \
  gl_lds16(Ag + (size_t)((CH)*64 + grow) * KDIM + (T)*64 + gcol * 8,           \
           (char*)&As[BUF][0] + (CH)*8192 + w * 1024)
#define STAGE_B(T, BUF, CH)                                                    \
  gl_lds16(Bg + (size_t)((CH)*64 + grow) * KDIM + (T)*64 + gcol * 8,           \
           (char*)&Bs[BUF][0] + (CH)*8192 + w * 1024)

#define LDA(CB, mi, ks)                                                        \
  (*(const bf16x8*)((const char*)&As[CB][0] +                                  \
                    (wr * 128 + (mi)*16 + l15) * 128 +                         \
                    ((((ks)*4 + kslc) ^ (l15 & 7)) << 4)))
#define LDB(CB, ni, ks)                                                        \
  (*(const bf16x8*)((const char*)&Bs[CB][0] +                                  \
                    (wc * 48 + (ni)*16 + l15) * 128 +                          \
                    ((((ks)*4 + kslc) ^ (l15 & 7)) << 4)))

#define CLUSTER12(B_, A0, A1, A2, A3, B0, B1, B2)                              \
  do {                                                                         \
    __builtin_amdgcn_s_setprio(1);                                             \
    acc[B_ + 0][0] = MFMA16(A0, B0, acc[B_ + 0][0]);                           \
    acc[B_ + 0][1] = MFMA16(A0, B1, acc[B_ + 0][1]);                           \
    acc[B_ + 0][2] = MFMA16(A0, B2, acc[B_ + 0][2]);                           \
    acc[B_ + 1][0] = MFMA16(A1, B0, acc[B_ + 1][0]);                           \
    acc[B_ + 1][1] = MFMA16(A1, B1, acc[B_ + 1][1]);                           \
    acc[B_ + 1][2] = MFMA16(A1, B2, acc[B_ + 1][2]);                           \
    acc[B_ + 2][0] = MFMA16(A2, B0, acc[B_ + 2][0]);                           \
    acc[B_ + 2][1] = MFMA16(A2, B1, acc[B_ + 2][1]);                           \
    acc[B_ + 2][2] = MFMA16(A2, B2, acc[B_ + 2][2]);                           \
    acc[B_ + 3][0] = MFMA16(A3, B0, acc[B_ + 3][0]);                           \
    acc[B_ + 3][1] = MFMA16(A3, B1, acc[B_ + 3][1]);                           \
    acc[B_ + 3][2] = MFMA16(A3, B2, acc[B_ + 3][2]);                           \
    __builtin_amdgcn_s_setprio(0);                                             \
  } while (0)

  // prologue: full K-tile 0 into buf 0 (7 loads/thread)
  STAGE_A(0, 0, 0); STAGE_A(0, 0, 1); STAGE_A(0, 0, 2); STAGE_A(0, 0, 3);
  STAGE_B(0, 0, 0); STAGE_B(0, 0, 1); STAGE_B(0, 0, 2);

#pragma unroll 1
  for (int t = 0; t < 15; ++t) {
    const int cb = t & 1, nb = cb ^ 1;
    STAGE_A(t + 1, nb, 0); STAGE_A(t + 1, nb, 1);
    asm volatile("s_waitcnt vmcnt(2)" ::: "memory");
    __builtin_amdgcn_s_barrier();
    {
      bf16x8 a0 = LDA(cb, 0, 0), a1 = LDA(cb, 1, 0), a2 = LDA(cb, 2, 0),
             a3 = LDA(cb, 3, 0);
      bf16x8 b0 = LDB(cb, 0, 0), b1 = LDB(cb, 1, 0), b2 = LDB(cb, 2, 0);
      CLUSTER12(0, a0, a1, a2, a3, b0, b1, b2);
      __builtin_amdgcn_s_barrier();
      bf16x8 a4 = LDA(cb, 4, 0), a5 = LDA(cb, 5, 0), a6 = LDA(cb, 6, 0),
             a7 = LDA(cb, 7, 0);
      STAGE_A(t + 1, nb, 2); STAGE_A(t + 1, nb, 3);
      __builtin_amdgcn_s_barrier();
      CLUSTER12(4, a4, a5, a6, a7, b0, b1, b2);
      __builtin_amdgcn_s_barrier();
      bf16x8 c0_ = LDA(cb, 0, 1), c1_ = LDA(cb, 1, 1), c2_ = LDA(cb, 2, 1),
             c3_ = LDA(cb, 3, 1);
      bf16x8 d0 = LDB(cb, 0, 1), d1 = LDB(cb, 1, 1), d2 = LDB(cb, 2, 1);
      STAGE_B(t + 1, nb, 0); STAGE_B(t + 1, nb, 1);
      __builtin_amdgcn_s_barrier();
      CLUSTER12(0, c0_, c1_, c2_, c3_, d0, d1, d2);
      __builtin_amdgcn_s_barrier();
      bf16x8 c4 = LDA(cb, 4, 1), c5 = LDA(cb, 5, 1), c6 = LDA(cb, 6, 1),
             c7 = LDA(cb, 7, 1);
      STAGE_B(t + 1, nb, 2);
      __builtin_amdgcn_s_barrier();
      CLUSTER12(4, c4, c5, c6, c7, d0, d1, d2);
      __builtin_amdgcn_s_barrier();
    }
  }
  asm volatile("s_waitcnt vmcnt(0)" ::: "memory");
  __builtin_amdgcn_s_barrier();
  {
    bf16x8 a0 = LDA(1, 0, 0), a1 = LDA(1, 1, 0), a2 = LDA(1, 2, 0),
           a3 = LDA(1, 3, 0);
    bf16x8 b0 = LDB(1, 0, 0), b1 = LDB(1, 1, 0), b2 = LDB(1, 2, 0);
    CLUSTER12(0, a0, a1, a2, a3, b0, b1, b2);
    bf16x8 a4 = LDA(1, 4, 0), a5 = LDA(1, 5, 0), a6 = LDA(1, 6, 0),
           a7 = LDA(1, 7, 0);
    CLUSTER12(4, a4, a5, a6, a7, b0, b1, b2);
    bf16x8 c0_ = LDA(1, 0, 1), c1_ = LDA(1, 1, 1), c2_ = LDA(1, 2, 1),
           c3_ = LDA(1, 3, 1);
    bf16x8 d0 = LDB(1, 0, 1), d1 = LDB(1, 1, 1), d2 = LDB(1, 2, 1);
    CLUSTER12(0, c0_, c1_, c2_, c3_, d0, d1, d2);
    bf16x8 c4 = LDA(1, 4, 1), c5 = LDA(1, 5, 1), c6 = LDA(1, 6, 1),
           c7 = LDA(1, 7, 1);
    CLUSTER12(4, c4, c5, c6, c7, d0, d1, d2);
  }
#undef STAGE_A
#undef STAGE_B
#undef LDA
#undef LDB
#undef CLUSTER12

#pragma unroll
  for (int ni = 0; ni < 3; ++ni) {
    const int col0 = c0 + wc * 48 + ni * 16;
    const int which = col0 >> 10;  // 0=q,1=k,2=v
    const int h = (col0 >> 6) & 15;
    const int dh = (col0 & 63) + l15;
    const float bv = bias[col0 + l15];
#pragma unroll
    for (int mi = 0; mi < 8; ++mi) {
      int row = r0 + wr * 128 + mi * 16 + (l >> 4) * 4;  // multiple of 4
      int b_ = row >> 11, t0 = row & 2047;
      if (which == 2) {
        u16x4 pk;
#pragma unroll
        for (int j = 0; j < 4; ++j) pk[j] = f2bf(acc[mi][ni][j] + bv);
        *(u16x4*)(vto + ((size_t)(b_ * H_N + h) * DH_N + dh) * T_DIM + t0) = pk;
      } else {
        float mul = (which == 0) ? 0.125f : 1.0f;
        unsigned short* dst = (which == 0) ? qo : ko;
#pragma unroll
        for (int j = 0; j < 4; ++j)
          dst[((size_t)(b_ * H_N + h) * T_DIM + t0 + j) * DH_N + dh] =
              f2bf((acc[mi][ni][j] + bv) * mul);
      }
    }
  }
}

// ---------------------------------------------------------------------------
// out-proj GEMM (unchanged): 128x128, quad-buffer, lead-2, one barrier/iter,
// counted vmcnt(8).
// ---------------------------------------------------------------------------
__global__ __launch_bounds__(256) void gemm_out_p4(
    const unsigned short* __restrict__ A, const unsigned short* __restrict__ Bt,
    const float* __restrict__ bias, float* __restrict__ fo) {
  __shared__ unsigned short As[4][4096];
  __shared__ unsigned short Bs[4][4096];

  const int tid = threadIdx.x;
  const int w = tid >> 6, l = tid & 63;
  const int wr = w >> 1, wc = w & 1;
  const int l15 = l & 15, kslc = l >> 4;

  const int id = blockIdx.x;
  const int wg = (id & 7) * 32 + (id >> 3);
  const int bx = wg & 7, by = wg >> 3;
  const int r0 = by * 128, c0 = bx * 128;

  const unsigned short* Ag = A + (size_t)r0 * KDIM;
  const unsigned short* Bg = Bt + (size_t)c0 * KDIM;

  f32x4 acc[4][4];
#pragma unroll
  for (int i = 0; i < 4; ++i)
#pragma unroll
    for (int j = 0; j < 4; ++j) acc[i][j] = (f32x4){0.f, 0.f, 0.f, 0.f};

  const int srow = l >> 2;
  const int srcslot = (l & 3) ^ ((l >> 3) & 3);

#define STAGE_O(T, BUF)                                                        \
  do {                                                                         \
    const size_t kk0 = (size_t)(T) * 32;                                       \
    gl_lds16(Ag + (size_t)(w * 16 + srow) * KDIM + kk0 + srcslot * 8,          \
             (char*)&As[BUF][0] + w * 1024);                                   \
    gl_lds16(Ag + (size_t)(64 + w * 16 + srow) * KDIM + kk0 + srcslot * 8,     \
             (char*)&As[BUF][0] + (4 + w) * 1024);                             \
    gl_lds16(Bg + (size_t)(w * 16 + srow) * KDIM + kk0 + srcslot * 8,          \
             (char*)&Bs[BUF][0] + w * 1024);                                   \
    gl_lds16(Bg + (size_t)(64 + w * 16 + srow) * KDIM + kk0 + srcslot * 8,     \
             (char*)&Bs[BUF][0] + (4 + w) * 1024);                             \
  } while (0)

#define OCOMPUTE(CB)                                                           \
  do {                                                                         \
    bf16x8 af[4], bfr[4];                                                      \
    _Pragma("unroll") for (int mi = 0; mi < 4; ++mi) {                         \
      int row = wr * 64 + mi * 16 + l15;                                       \
      af[mi] = *(const bf16x8*)((const char*)&As[CB][0] + row * 64 +           \
                                ((kslc ^ ((row >> 1) & 3)) << 4));             \
    }                                                                          \
    _Pragma("unroll") for (int ni = 0; ni < 4; ++ni) {                         \
      int row = wc * 64 + ni * 16 + l15;                                       \
      bfr[ni] = *(const bf16x8*)((const char*)&Bs[CB][0] + row * 64 +          \
                                 ((kslc ^ ((row >> 1) & 3)) << 4));            \
    }                                                                          \
    __builtin_amdgcn_s_setprio(1);                                             \
    _Pragma("unroll") for (int mi = 0; mi < 4; ++mi)                           \
        _Pragma("unroll") for (int ni = 0; ni < 4; ++ni) acc[mi][ni] =         \
            MFMA16(af[mi], bfr[ni], acc[mi][ni]);                              \
    __builtin_amdgcn_s_setprio(0);                                             \
  } while (0)

  STAGE_O(0, 0);
  STAGE_O(1, 1);

  for (int t = 0; t < 30; ++t) {
    STAGE_O(t + 2, (t + 2) & 3);
    asm volatile("s_waitcnt vmcnt(8)" ::: "memory");
    __builtin_amdgcn_s_barrier();
    OCOMPUTE(t & 3);
  }
  asm volatile("s_waitcnt vmcnt(4)" ::: "memory");
  __builtin_amdgcn_s_barrier();
  OCOMPUTE(2);
  asm volatile("s_waitcnt vmcnt(0)" ::: "memory");
  __builtin_amdgcn_s_barrier();
  OCOMPUTE(3);
#undef STAGE_O
#undef OCOMPUTE

#pragma unroll
  for (int mi = 0; mi < 4; ++mi) {
#pragma unroll
    for (int ni = 0; ni < 4; ++ni) {
      int row = r0 + wr * 64 + mi * 16 + (l >> 4) * 4;
      int col = c0 + wc * 64 + ni * 16 + l15;
      float bv = bias[col];
#pragma unroll
      for (int j = 0; j < 4; ++j)
        fo[(size_t)(row + j) * D_DIM + col] = acc[mi][ni][j] + bv;
    }
  }
}

// ---------------------------------------------------------------------------
// attn_mono: stage the ENTIRE window (<=5 K/V tiles, 80KB LDS) once, one
// vmcnt(0)+barrier, then all tiles computed back-to-back with NO further
// barriers (tiles independent -> compiler overlaps softmax VALU with next
// tile's QK MFMAs). 2 blocks/CU; 1024 blocks = 2 launch-waves.
// ---------------------------------------------------------------------------
__global__ __launch_bounds__(256) void attn_mono(
    const unsigned short* __restrict__ qbf,
    const unsigned short* __restrict__ kbf,
    const unsigned short* __restrict__ vtbf,
    unsigned short* __restrict__ ctx) {
  __shared__ unsigned short Ks[5 * 4096];  // 5 tiles x 8KB
  __shared__ unsigned short Vs[5 * 4096];
  const int tid = threadIdx.x;
  const int w = tid >> 6, l = tid & 63;
  const int g = l >> 4, ln = l & 15;
  const int qt = blockIdx.x & 31;
  const int bh = blockIdx.x >> 5;
  const int q0 = qt * 64;
  const int q_abs = q0 + w * 16 + ln;

  const unsigned short* kp = kbf + (size_t)bh * T_DIM * DH_N;
  const unsigned short* vtp = vtbf + (size_t)bh * DH_N * T_DIM;

  bf16x8 qf0, qf1;
  {
    const unsigned short* qp = qbf + ((size_t)bh * T_DIM + q_abs) * DH_N;
    qf0 = *(const bf16x8*)(qp + g * 8);
    qf1 = *(const bf16x8*)(qp + 32 + g * 8);
  }

#define KAP(row) \
  (32 * (((row) >> 4) & 1) + 8 * (((row)&15) >> 2) + 4 * ((row) >> 5) + ((row)&3))

  const int kt_lo = (q0 >= WIN) ? (q0 - WIN) : 0;
  const int nt = ((q0 - kt_lo) >> 6) + 1;

  // stage all nt tiles (4 gl_lds16/thread per tile, <=20 total)
  for (int i = 0; i < nt; ++i) {
    const int kt = kt_lo + i * 64;
#pragma unroll
    for (int i_ = 0; i_ < 2; ++i_) {
      int chunk = i_ * 256 + tid;
      int row = chunk >> 3, c16 = chunk & 7;
      int sc16 = c16 ^ (row & 7);
      int kap = KAP(row);
      gl_lds16(kp + (size_t)(kt + kap) * DH_N + sc16 * 8,
               (char*)Ks + i * 8192 + chunk * 16);
      gl_lds16(vtp + (size_t)row * T_DIM + kt + sc16 * 8,
               (char*)Vs + i * 8192 + chunk * 16);
    }
  }
  asm volatile("s_waitcnt vmcnt(0)" ::: "memory");
  __builtin_amdgcn_s_barrier();  // all window data resident; no more barriers

  f32x4 acc_o[4];
#pragma unroll
  for (int nd = 0; nd < 4; ++nd) acc_o[nd] = (f32x4){0.f, 0.f, 0.f, 0.f};
  float m = -1e30f, lsum = 0.f;

  for (int i = 0; i < nt; ++i) {
    const int kt = kt_lo + i * 64;
    const char* Kb = (const char*)Ks + i * 8192;
    const char* Vb = (const char*)Vs + i * 8192;

    // S^T = K · Q^T
    f32x4 sacc[4];
#pragma unroll
    for (int nk = 0; nk < 4; ++nk) sacc[nk] = (f32x4){0.f, 0.f, 0.f, 0.f};
#pragma unroll
    for (int ks = 0; ks < 2; ++ks) {
      bf16x8 qf = ks ? qf1 : qf0;
#pragma unroll
      for (int nk = 0; nk < 4; ++nk) {
        int rrow = nk * 16 + ln;
        int c16 = ks * 4 + g;
        bf16x8 kf =
            *(const bf16x8*)(Kb + rrow * 128 + ((c16 ^ (rrow & 7)) * 16));
        sacc[nk] = MFMA16(kf, qf, sacc[nk]);
      }
    }

    float p[4][4];
    float tm = -1e30f;
#pragma unroll
    for (int nk = 0; nk < 4; ++nk)
#pragma unroll
      for (int j = 0; j < 4; ++j) {
        int k_abs = kt + 32 * (nk & 1) + 8 * g + 4 * (nk >> 1) + j;
        float s = sacc[nk][j];
        bool ok = (k_abs <= q_abs) && (k_abs + WIN >= q_abs);
        s = ok ? s : -1e30f;
        p[nk][j] = s;
        tm = fmaxf(tm, s);
      }
    tm = fmaxf(tm, __shfl_xor(tm, 16, 64));
    tm = fmaxf(tm, __shfl_xor(tm, 32, 64));
    float mn = fmaxf(m, tm);
    float sc = __expf(m - mn);
    float ps = 0.f;
#pragma unroll
    for (int nk = 0; nk < 4; ++nk)
#pragma unroll
      for (int j = 0; j < 4; ++j) {
        p[nk][j] = __expf(p[nk][j] - mn);
        ps += p[nk][j];
      }
    ps += __shfl_xor(ps, 16, 64);
    ps += __shfl_xor(ps, 32, 64);
    lsum = lsum * sc + ps;
    m = mn;
#pragma unroll
    for (int nd = 0; nd < 4; ++nd) {
      acc_o[nd][0] *= sc; acc_o[nd][1] *= sc;
      acc_o[nd][2] *= sc; acc_o[nd][3] *= sc;
    }

    unsigned int pk[4][2];
#pragma unroll
    for (int nk = 0; nk < 4; ++nk) {
      pk[nk][0] = (unsigned)f2bf(p[nk][0]) | ((unsigned)f2bf(p[nk][1]) << 16);
      pk[nk][1] = (unsigned)f2bf(p[nk][2]) | ((unsigned)f2bf(p[nk][3]) << 16);
    }

#pragma unroll
    for (int ks = 0; ks < 2; ++ks) {
      union { unsigned int d[4]; bf16x8 v; } pf;
      pf.d[0] = pk[ks][0];     pf.d[1] = pk[ks][1];
      pf.d[2] = pk[2 + ks][0]; pf.d[3] = pk[2 + ks][1];
#pragma unroll
      for (int nd = 0; nd < 4; ++nd) {
        int drow = nd * 16 + ln;
        int c16 = ks * 4 + g;
        bf16x8 vf =
            *(const bf16x8*)(Vb + drow * 128 + ((c16 ^ (drow & 7)) * 16));
        acc_o[nd] = MFMA16(vf, pf.v, acc_o[nd]);
      }
    }
  }
#undef KAP

  float inv = 1.f / lsum;
  const int b_ = bh >> 4, h = bh & 15;
  unsigned short* op = ctx + ((size_t)b_ * T_DIM + q_abs) * D_DIM + h * DH_N;
#pragma unroll
  for (int nd = 0; nd < 4; ++nd) {
    u16x4 o;
#pragma unroll
    for (int j = 0; j < 4; ++j) o[j] = f2bf(acc_o[nd][j] * inv);
    *(u16x4*)(op + nd * 16 + g * 4) = o;
  }
}

// ---------------------------------------------------------------------------
extern "C" void kernel_launch(void* const* d_in, const int* in_sizes, int n_in,
                              void* d_out, int out_size, void* d_ws,
                              size_t ws_size, hipStream_t stream) {
  const float* x = (const float*)d_in[0];
  const float* w_qkv = (const float*)d_in[1];
  const float* b_qkv = (const float*)d_in[2];
  const float* w_out = (const float*)d_in[3];
  const float* b_out = (const float*)d_in[4];
  float* out = (float*)d_out;

  const size_t per = (size_t)BN * H_N * T_DIM * DH_N;  // 4,194,304
  unsigned short* qbf = (unsigned short*)d_ws;
  unsigned short* kbf = qbf + per;
  unsigned short* vtbf = kbf + per;                    // [B,H,64,T]
  unsigned short* xbf = vtbf + per;                    // [4096][1024]
  unsigned short* wqkvt = xbf + (size_t)NROWS * D_DIM; // [3072][1024]
  unsigned short* woutt = wqkvt + (size_t)3 * D_DIM * D_DIM;  // [1024][1024]
  unsigned short* ctxbf = woutt + (size_t)D_DIM * D_DIM;      // [4096][1024]

  convert_all<<<dim3(3072), dim3(256), 0, stream>>>(x, w_qkv, w_out, xbf,
                                                    wqkvt, woutt);

  // qkv: 256x192 tiles -> 16 x 16 = 256 blocks, 512 threads
  gemm_qkv_8p<<<dim3(256), dim3(512), 0, stream>>>(xbf, wqkvt, b_qkv, qbf, kbf,
                                                   vtbf);

  attn_mono<<<dim3(BN * H_N * (T_DIM / 64)), dim3(256), 0, stream>>>(
      qbf, kbf, vtbf, ctxbf);

  // out-proj: 128x128 tiles -> 32 x 8 = 256 blocks, 256 threads
  gemm_out_p4<<<dim3(256), dim3(256), 0, stream>>>(ctxbf, woutt, b_out, out);
}